// Round 9
// baseline (979.806 us; speedup 1.0000x reference)
//
#include <hip/hip_runtime.h>
#include <stdint.h>

__device__ __forceinline__ float bf2f(unsigned short u) {
    union { unsigned u; float f; } v; v.u = ((unsigned)u) << 16; return v.f;
}
__device__ __forceinline__ unsigned short f2bf(float f) {
    union { float f; unsigned u; } v; v.f = f;
    unsigned r = v.u + 0x7fffu + ((v.u >> 16) & 1u);
    return (unsigned short)(r >> 16);
}

// B=4, T=1024, D=512, H=8, DH=64, MAX_REL=256.
// Inputs fp32, dict order (R2 NaN proof + R8 probe/idx_x evidence).
// OUTPUT IS FP32 (harness rule: reference returns float32). Previous rounds
// wrote bf16 into the fp32 buffer -> scrambled readback -> the constant 6.671875.

// ---------- 1. xsum[b][k] = sum_t x[b,t,k] ----------
__global__ void xsum_kernel(const float* __restrict__ x, float* __restrict__ xsum) {
    int b = blockIdx.x, k = threadIdx.x;            // 4 x 512
    const float* p = x + (size_t)b * 1024 * 512 + k;
    float s = 0.f;
    for (int t = 0; t < 1024; ++t) s += p[t * 512];
    xsum[b * 512 + k] = s;
}

// ---------- 2. Qsum[b][n] = xsum[b]·Wq[n,:] + 1024*bq[n] ----------
__global__ void qsum_kernel(const float* __restrict__ xsum, const float* __restrict__ Wq,
                            const float* __restrict__ bq, float* __restrict__ Qsum) {
    int idx = blockIdx.x * 256 + threadIdx.x;       // 8 x 256 = 2048
    int b = idx >> 9, n = idx & 511;
    const float* xs = xsum + b * 512;
    const float* w = Wq + (size_t)n * 512;
    float s = 0.f;
    for (int k = 0; k < 512; ++k) s += xs[k] * w[k];
    Qsum[idx] = s + 1024.0f * bq[n];
}

// ---------- 3. R[bh*513 + delta] = 0.125 * Qsum[b,h*64:+64]·rel_table[delta] ----------
__global__ void rbias_kernel(const float* __restrict__ Qsum, const float* __restrict__ relT,
                             float* __restrict__ R) {
    int idx = blockIdx.x * 256 + threadIdx.x;
    if (idx >= 4 * 8 * 513) return;
    int delta = idx % 513, bh = idx / 513;
    int b = bh >> 3, h = bh & 7;
    const float* qs = Qsum + b * 512 + h * 64;
    const float* rt = relT + (size_t)delta * 64;
    float s = 0.f;
    for (int d = 0; d < 64; ++d) s += qs[d] * rt[d];
    R[idx] = 0.125f * s;
}

// ---------- 4. QKV projection (VALU f32 GEMM): y = x @ W^T + b -> (B,H,T,DH) bf16 ----------
// probe-verified in R8 (Qb matched brute-force x·Wq)
__global__ __launch_bounds__(256) void qkv_proj_f32(
    const float* __restrict__ x,
    const float* __restrict__ Wq, const float* __restrict__ bq,
    const float* __restrict__ Wk, const float* __restrict__ bk,
    const float* __restrict__ Wv, const float* __restrict__ bv,
    unsigned short* __restrict__ Qb, unsigned short* __restrict__ Kb, unsigned short* __restrict__ Vb) {
    const int which = blockIdx.z;
    const float* W; const float* bias; unsigned short* Out;
    if (which == 0)      { W = Wq; bias = bq; Out = Qb; }
    else if (which == 1) { W = Wk; bias = bk; Out = Kb; }
    else                 { W = Wv; bias = bv; Out = Vb; }
    const int m0 = blockIdx.y * 64;
    const int n0 = blockIdx.x * 64;

    __shared__ float As[64][17];
    __shared__ float Ws_[64][17];
    int tid = threadIdx.x, ty = tid >> 4, tx = tid & 15;

    float acc[4][4] = {};
    for (int k0 = 0; k0 < 512; k0 += 16) {
        for (int l = 0; l < 4; ++l) {
            int e = tid + l * 256, r = e >> 4, c = e & 15;
            As[r][c]  = x[(size_t)(m0 + r) * 512 + k0 + c];
            Ws_[r][c] = W[(size_t)(n0 + r) * 512 + k0 + c];
        }
        __syncthreads();
        for (int kk = 0; kk < 16; ++kk) {
            float a[4], w[4];
            for (int i = 0; i < 4; ++i) a[i] = As[ty * 4 + i][kk];
            for (int j = 0; j < 4; ++j) w[j] = Ws_[tx * 4 + j][kk];
            for (int i = 0; i < 4; ++i)
                for (int j = 0; j < 4; ++j) acc[i][j] += a[i] * w[j];
        }
        __syncthreads();
    }
    for (int i = 0; i < 4; ++i) {
        int row = m0 + ty * 4 + i;           // = b*1024 + t
        int b = row >> 10, t = row & 1023;
        for (int j = 0; j < 4; ++j) {
            int col = n0 + tx * 4 + j;
            int h = col >> 6, d = col & 63;
            Out[(((size_t)(b * 8 + h) * 1024 + t) << 6) + d] = f2bf(acc[i][j] + bias[col]);
        }
    }
}

// ---------- 5. fused flash attention + output projection (fp32 atomics into d_out) ----
// block = (bh, 16 query rows). After online-softmax PV, project the 16x64 head tile
// through Wo[:, h*64:+64] and atomicAdd into out[b, t, :] (fp32). h==0 adds bo.
__global__ __launch_bounds__(256) void attn_fused(
    const unsigned short* __restrict__ Qb, const unsigned short* __restrict__ Kb,
    const unsigned short* __restrict__ Vb, const float* __restrict__ R,
    const float* __restrict__ Wo, const float* __restrict__ bo,
    float* __restrict__ out) {
    const int bh = blockIdx.y;               // 32
    const int i0 = blockIdx.x * 16;          // 64 tiles of 16 query rows
    const int b = bh >> 3, h = bh & 7;

    __shared__ float Qs[16][68];
    __shared__ float Ks[64][68];
    __shared__ float Vs[64][68];
    __shared__ float Ps[16][68];
    __shared__ float Os[16][68];
    __shared__ float Rs[513];

    int tid = threadIdx.x, g = tid >> 4, e = tid & 15;

    for (int c = tid; c < 513; c += 256) Rs[c] = R[bh * 513 + c];
    for (int c = tid; c < 1024; c += 256) {
        int r = c >> 6, d = c & 63;
        Qs[r][d] = bf2f(Qb[((size_t)bh * 1024 + i0 + r) * 64 + d]);
    }

    const unsigned short* Kp = Kb + (size_t)bh * 1024 * 64;
    const unsigned short* Vp = Vb + (size_t)bh * 1024 * 64;

    float m_run = -1e30f, l_run = 0.f;
    float oacc[4] = {0.f, 0.f, 0.f, 0.f};    // thread e holds dh = di*16 + e
    const int qi = i0 + g;

    for (int s0 = 0; s0 < 1024; s0 += 64) {
        __syncthreads();
        for (int c = tid; c < 4096; c += 256) {
            int r = c >> 6, d = c & 63;
            Ks[r][d] = bf2f(Kp[(size_t)(s0 + r) * 64 + d]);
            Vs[r][d] = bf2f(Vp[(size_t)(s0 + r) * 64 + d]);
        }
        __syncthreads();

        float sc[4], mx = -1e30f;
        for (int jj = 0; jj < 4; ++jj) {
            int j = jj * 16 + e;
            float s = 0.f;
            for (int d = 0; d < 64; ++d) s += Qs[g][d] * Ks[j][d];
            int dlt = (s0 + j) - qi;
            dlt = dlt > 256 ? 256 : (dlt < -256 ? -256 : dlt);
            s = s * 0.125f + Rs[dlt + 256];
            sc[jj] = s;
            mx = fmaxf(mx, s);
        }
        for (int off = 1; off < 16; off <<= 1) mx = fmaxf(mx, __shfl_xor(mx, off, 64));
        float mnew = fmaxf(m_run, mx);
        float alpha = __expf(m_run - mnew);
        float rs = 0.f;
        for (int jj = 0; jj < 4; ++jj) {
            float p = __expf(sc[jj] - mnew);
            Ps[g][jj * 16 + e] = p;           // same-wave group-private row
            rs += p;
        }
        for (int off = 1; off < 16; off <<= 1) rs += __shfl_xor(rs, off, 64);
        l_run = l_run * alpha + rs;
        m_run = mnew;
        for (int di = 0; di < 4; ++di) oacc[di] *= alpha;

        for (int j = 0; j < 64; ++j) {
            float pv = Ps[g][j];
            for (int di = 0; di < 4; ++di) oacc[di] += pv * Vs[j][di * 16 + e];
        }
    }

    // stage normalized head-output tile, then project through Wo slice + atomic add
    for (int di = 0; di < 4; ++di) Os[g][di * 16 + e] = oacc[di] / l_run;
    __syncthreads();

    for (int p = tid; p < 16 * 512; p += 256) {
        int row = p >> 9, n = p & 511;       // consecutive tid -> consecutive n
        const float* w = Wo + (size_t)n * 512 + h * 64;
        float s = 0.f;
        for (int dh = 0; dh < 64; ++dh) s += Os[row][dh] * w[dh];
        if (h == 0) s += bo[n];
        atomicAdd(&out[(size_t)(b * 1024 + i0 + row) * 512 + n], s);
    }
}

extern "C" void kernel_launch(void* const* d_in, const int* in_sizes, int n_in,
                              void* d_out, int out_size, void* d_ws, size_t ws_size,
                              hipStream_t stream) {
    // bind by size; established: dict order (x first). Keep size-binder for safety.
    const void* x = nullptr; const void* Ws[4] = {}; const void* bs[4] = {};
    const void* relT = nullptr;
    int wi = 0, bi = 0, idx_x = -1;
    for (int i = 0; i < n_in; ++i) {
        long s = in_sizes[i];
        if ((s == 2097152 || s == 8388608) && !x) { x = d_in[i]; idx_x = i; }
        else if ((s == 262144 || s == 1048576) && wi < 4) Ws[wi++] = d_in[i];
        else if ((s == 512 || s == 2048) && bi < 4) bs[bi++] = d_in[i];
        else if ((s == 32832 || s == 131328) && !relT) relT = d_in[i];
    }
    const float *Wq, *Wk, *Wv, *Wo, *bq, *bk, *bv, *bo;
    if (x && wi == 4 && bi == 4 && relT) {
        bool sorted_order = (idx_x != 0);    // measured: idx_x==0 -> dict order
        if (sorted_order) {
            Wq = (const float*)Ws[2]; Wk = (const float*)Ws[0];
            Wv = (const float*)Ws[3]; Wo = (const float*)Ws[1];
            bq = (const float*)bs[2]; bk = (const float*)bs[0];
            bv = (const float*)bs[3]; bo = (const float*)bs[1];
        } else {
            Wq = (const float*)Ws[0]; Wk = (const float*)Ws[1];
            Wv = (const float*)Ws[2]; Wo = (const float*)Ws[3];
            bq = (const float*)bs[0]; bk = (const float*)bs[1];
            bv = (const float*)bs[2]; bo = (const float*)bs[3];
        }
    } else {
        x = d_in[0];
        Wq = (const float*)d_in[2]; bq = (const float*)d_in[3];
        Wk = (const float*)d_in[4]; bk = (const float*)d_in[5];
        Wv = (const float*)d_in[6]; bv = (const float*)d_in[7];
        Wo = (const float*)d_in[8]; bo = (const float*)d_in[9];
        relT = d_in[10];
    }
    const float* xf  = (const float*)x;
    const float* rel = (const float*)relT;
    float* out = (float*)d_out;              // FP32 OUTPUT

    // ws: 8KB + 8KB + 66KB + 3x4MB = 12.1 MB
    char* ws = (char*)d_ws;
    float* xsum = (float*)(ws);
    float* Qsum = (float*)(ws + 8192);
    float* Rbuf = (float*)(ws + 16384);
    unsigned short* Qb = (unsigned short*)(ws + 131072);
    unsigned short* Kb = (unsigned short*)(ws + 131072 + (4 << 20));
    unsigned short* Vb = (unsigned short*)(ws + 131072 + (8 << 20));

    hipMemsetAsync(out, 0, (size_t)out_size * sizeof(float), stream);  // atomic accum base
    xsum_kernel<<<dim3(4), dim3(512), 0, stream>>>(xf, xsum);
    qsum_kernel<<<dim3(8), dim3(256), 0, stream>>>(xsum, Wq, bq, Qsum);
    rbias_kernel<<<dim3(65), dim3(256), 0, stream>>>(Qsum, rel, Rbuf);
    qkv_proj_f32<<<dim3(8, 64, 3), dim3(256), 0, stream>>>(xf, Wq, bq, Wk, bk, Wv, bv, Qb, Kb, Vb);
    attn_fused<<<dim3(64, 32), dim3(256), 0, stream>>>(Qb, Kb, Vb, Rbuf, Wo, bo, out);
}

// Round 10
// 246.778 us; speedup vs baseline: 3.9704x; 3.9704x over previous
//
#include <hip/hip_runtime.h>
#include <stdint.h>

typedef __bf16  bf16x8 __attribute__((ext_vector_type(8)));
typedef float   f32x4  __attribute__((ext_vector_type(4)));

#define MFMA16(a, b, c) __builtin_amdgcn_mfma_f32_16x16x32_bf16((a), (b), (c), 0, 0, 0)

__device__ __forceinline__ float bf2f(unsigned short u) {
    union { unsigned u; float f; } v; v.u = ((unsigned)u) << 16; return v.f;
}
__device__ __forceinline__ unsigned short f2bf(float f) {
    union { float f; unsigned u; } v; v.f = f;
    unsigned r = v.u + 0x7fffu + ((v.u >> 16) & 1u);
    return (unsigned short)(r >> 16);
}

// B=4, T=1024, D=512, H=8, DH=64, MAX_REL=256.
// Inputs fp32 dict-order; OUTPUT FP32 (established R9). MFMA pipeline restored.

// ---------- 1. xsum[b][k] = sum_t x[b,t,k] ----------
__global__ void xsum_kernel(const float* __restrict__ x, float* __restrict__ xsum) {
    int b = blockIdx.x, k = threadIdx.x;            // 4 x 512
    const float* p = x + (size_t)b * 1024 * 512 + k;
    float s = 0.f;
    for (int t = 0; t < 1024; ++t) s += p[t * 512];
    xsum[b * 512 + k] = s;
}

// ---------- 2. Qsum[b][n] = xsum[b]·Wq[n,:] + 1024*bq[n] ----------
__global__ void qsum_kernel(const float* __restrict__ xsum, const float* __restrict__ Wq,
                            const float* __restrict__ bq, float* __restrict__ Qsum) {
    int idx = blockIdx.x * 256 + threadIdx.x;       // 8 x 256 = 2048
    int b = idx >> 9, n = idx & 511;
    const float* xs = xsum + b * 512;
    const float* w = Wq + (size_t)n * 512;
    float s = 0.f;
    for (int k = 0; k < 512; ++k) s += xs[k] * w[k];
    Qsum[idx] = s + 1024.0f * bq[n];
}

// ---------- 3. R[bh*513 + delta] = 0.125 * Qsum[b,h*64:+64]·rel_table[delta] ----------
__global__ void rbias_kernel(const float* __restrict__ Qsum, const float* __restrict__ relT,
                             float* __restrict__ R) {
    int idx = blockIdx.x * 256 + threadIdx.x;
    if (idx >= 4 * 8 * 513) return;
    int delta = idx % 513, bh = idx / 513;
    int b = bh >> 3, h = bh & 7;
    const float* qs = Qsum + b * 512 + h * 64;
    const float* rt = relT + (size_t)delta * 64;
    float s = 0.f;
    for (int d = 0; d < 64; ++d) s += qs[d] * rt[d];
    R[idx] = 0.125f * s;
}

// ---------- fp32 64x64 tile (ld=512) -> bf16 LDS [64][72] ----------
__device__ __forceinline__ void stage_f32(const float* __restrict__ src, int row0, int k0,
                                          unsigned short (*dst)[72], int tid) {
    for (int c = tid; c < 1024; c += 256) {
        int row = c >> 4, kc = (c & 15) << 2;
        f32x4 v = *(const f32x4*)(src + (size_t)(row0 + row) * 512 + k0 + kc);
        ushort4 r;
        r.x = f2bf(v[0]); r.y = f2bf(v[1]); r.z = f2bf(v[2]); r.w = f2bf(v[3]);
        *(ushort4*)(&dst[row][kc]) = r;
    }
}

// ---------- 4. QKV projection (MFMA): y = x @ W^T + b -> (B,H,T,DH) bf16 ----------
__global__ __launch_bounds__(256) void qkv_proj(
    const float* __restrict__ x,
    const float* __restrict__ Wq, const float* __restrict__ bq,
    const float* __restrict__ Wk, const float* __restrict__ bk,
    const float* __restrict__ Wv, const float* __restrict__ bv,
    unsigned short* __restrict__ Qb, unsigned short* __restrict__ Kb, unsigned short* __restrict__ Vb) {
    const int which = blockIdx.z;
    const float* W; const float* bias; unsigned short* Out;
    if (which == 0)      { W = Wq; bias = bq; Out = Qb; }
    else if (which == 1) { W = Wk; bias = bk; Out = Kb; }
    else                 { W = Wv; bias = bv; Out = Vb; }
    const int m0 = blockIdx.y * 64;   // rows (b*1024+t)
    const int n0 = blockIdx.x * 64;   // output feature

    __shared__ __align__(16) unsigned short As[64][72];
    __shared__ __align__(16) unsigned short Bs[64][72];

    int tid = threadIdx.x;
    int wave = tid >> 6, lane = tid & 63, quad = lane >> 4, l16 = lane & 15;
    int arow = wave * 16 + l16;

    f32x4 acc[4] = {};

    for (int k0 = 0; k0 < 512; k0 += 64) {
        stage_f32(x, m0, k0, As, tid);
        stage_f32(W, n0, k0, Bs, tid);
        __syncthreads();
        for (int kk = 0; kk < 2; ++kk) {
            bf16x8 af = *(const bf16x8*)(&As[arow][kk * 32 + quad * 8]);
            for (int nt = 0; nt < 4; ++nt) {
                bf16x8 bfv = *(const bf16x8*)(&Bs[nt * 16 + l16][kk * 32 + quad * 8]);
                acc[nt] = MFMA16(af, bfv, acc[nt]);
            }
        }
        __syncthreads();
    }
    // C: row = m0+wave*16+quad*4+reg, col = n0+nt*16+l16  (m89-verified)
    for (int nt = 0; nt < 4; ++nt) {
        int col = n0 + nt * 16 + l16;
        int h = col >> 6, d = col & 63;
        float bv_ = bias[col];
        for (int reg = 0; reg < 4; ++reg) {
            int row = m0 + wave * 16 + quad * 4 + reg;     // = b*1024 + t
            int b = row >> 10, t = row & 1023;
            Out[(((size_t)(b * 8 + h) * 1024 + t) << 6) + d] = f2bf(acc[nt][reg] + bv_);
        }
    }
}

// ---------- 5. MFMA flash attention per (b,h, 64-row q-tile) ----------
// Writes head output bf16 IN-PLACE over this block's private Qb slice (B,H,T,DH).
__global__ __launch_bounds__(256) void attn_kernel(
    unsigned short* __restrict__ Qb,                     // also AO output
    const unsigned short* __restrict__ Kb, const unsigned short* __restrict__ Vb,
    const float* __restrict__ R) {
    const int bh = blockIdx.y;           // 32
    const int t0 = blockIdx.x * 64;      // 16 tiles
    __shared__ __align__(16) unsigned short Ks[64][72];  // K[s][dh]
    __shared__ __align__(16) unsigned short Vt[64][72];  // V^T[dh][s]
    __shared__ __align__(16) unsigned short Ps[64][72];  // P[t][s] bf16
    __shared__ float Rs[513];

    int tid = threadIdx.x, wave = tid >> 6, lane = tid & 63, quad = lane >> 4, l16 = lane & 15;

    for (int i = tid; i < 513; i += 256) Rs[i] = R[bh * 513 + i];

    unsigned short* Qp = Qb + ((size_t)bh * 1024 + t0) * 64;
    int arow = wave * 16 + l16;
    bf16x8 qf0 = *(const bf16x8*)(Qp + arow * 64 + quad * 8);
    bf16x8 qf1 = *(const bf16x8*)(Qp + arow * 64 + 32 + quad * 8);

    const unsigned short* Kp = Kb + (size_t)bh * 1024 * 64;
    const unsigned short* Vp = Vb + (size_t)bh * 1024 * 64;

    f32x4 acco[4] = {};
    float m_run[4], l_run[4];
    for (int r = 0; r < 4; ++r) { m_run[r] = -1e30f; l_run[r] = 0.f; }

    for (int s0 = 0; s0 < 1024; s0 += 64) {
        __syncthreads();   // protect LDS reuse (and Rs on iter 0)
        for (int c = tid; c < 512; c += 256) {
            int row = c >> 3, kc = (c & 7) << 3;
            *(uint4*)(&Ks[row][kc]) = *(const uint4*)(Kp + (size_t)(s0 + row) * 64 + kc);
            uint4 vv = *(const uint4*)(Vp + (size_t)(s0 + row) * 64 + kc);
            const unsigned short* ve = (const unsigned short*)&vv;
            for (int j = 0; j < 8; ++j) Vt[kc + j][row] = ve[j];   // transpose
        }
        __syncthreads();

        // S = Q K^T
        f32x4 accs[4] = {};
        for (int nt = 0; nt < 4; ++nt) {
            bf16x8 kf0 = *(const bf16x8*)(&Ks[nt * 16 + l16][quad * 8]);
            accs[nt] = MFMA16(qf0, kf0, accs[nt]);
            bf16x8 kf1 = *(const bf16x8*)(&Ks[nt * 16 + l16][32 + quad * 8]);
            accs[nt] = MFMA16(qf1, kf1, accs[nt]);
        }

        // bias + online softmax (intra-quad shuffles)
        float sv[4][4], mnew[4], alpha[4];
        for (int reg = 0; reg < 4; ++reg) {
            int tt = t0 + wave * 16 + quad * 4 + reg;
            float mx = -1e30f;
            for (int nt = 0; nt < 4; ++nt) {
                int ss = s0 + nt * 16 + l16;
                int dlt = ss - tt;
                dlt = dlt > 256 ? 256 : (dlt < -256 ? -256 : dlt);
                float v = accs[nt][reg] * 0.125f + Rs[dlt + 256];
                sv[nt][reg] = v;
                mx = fmaxf(mx, v);
            }
            for (int off = 1; off < 16; off <<= 1) mx = fmaxf(mx, __shfl_xor(mx, off, 64));
            mnew[reg] = fmaxf(m_run[reg], mx);
        }
        for (int reg = 0; reg < 4; ++reg) {
            float rs = 0.f;
            for (int nt = 0; nt < 4; ++nt) {
                float p = __expf(sv[nt][reg] - mnew[reg]);
                rs += p;
                Ps[wave * 16 + quad * 4 + reg][nt * 16 + l16] = f2bf(p);
            }
            for (int off = 1; off < 16; off <<= 1) rs += __shfl_xor(rs, off, 64);
            alpha[reg] = __expf(m_run[reg] - mnew[reg]);
            l_run[reg] = l_run[reg] * alpha[reg] + rs;
            m_run[reg] = mnew[reg];
        }
        for (int nt = 0; nt < 4; ++nt)
            for (int reg = 0; reg < 4; ++reg) acco[nt][reg] *= alpha[reg];

        __syncthreads();   // Ps/Vt ordered before PV

        for (int kk = 0; kk < 2; ++kk) {
            bf16x8 pf = *(const bf16x8*)(&Ps[wave * 16 + l16][kk * 32 + quad * 8]);
            for (int nt = 0; nt < 4; ++nt) {
                bf16x8 vf = *(const bf16x8*)(&Vt[nt * 16 + l16][kk * 32 + quad * 8]);
                acco[nt] = MFMA16(pf, vf, acco[nt]);
            }
        }
    }

    // write AO bf16 over our own Qb slice (B,H,T,DH layout)
    for (int nt = 0; nt < 4; ++nt) {
        for (int reg = 0; reg < 4; ++reg) {
            int tt = t0 + wave * 16 + quad * 4 + reg;
            int d = nt * 16 + l16;
            Qp[(size_t)(tt - t0) * 64 + 0] = Qp[(tt - t0) * 64];  // no-op to keep layout obvious
            Qb[((size_t)bh * 1024 + tt) * 64 + d] = f2bf(acco[nt][reg] / l_run[reg]);
        }
    }
}

// ---------- 6. output projection (MFMA): out = AO_headconcat @ Wo^T + bo, fp32 ----------
// AO is bf16 in (B,H,T,DH) layout (= old Qb). A[m=b*1024+t][k=h*64+dh].
__global__ __launch_bounds__(256) void out_proj(
    const unsigned short* __restrict__ AObf, const float* __restrict__ Wo,
    const float* __restrict__ bo, float* __restrict__ out) {
    const int m0 = blockIdx.y * 64;      // 64 m-tiles; b constant per tile
    const int n0 = blockIdx.x * 64;      // 8 n-tiles
    const int b = m0 >> 10, tt0 = m0 & 1023;
    __shared__ __align__(16) unsigned short As[64][72];
    __shared__ __align__(16) unsigned short Bs[64][72];
    int tid = threadIdx.x, wave = tid >> 6, lane = tid & 63, quad = lane >> 4, l16 = lane & 15;
    int arow = wave * 16 + l16;
    f32x4 acc[4] = {};
    for (int k0 = 0; k0 < 512; k0 += 64) {
        const int h = k0 >> 6;
        for (int c = tid; c < 512; c += 256) {   // A tile from head-h slice
            int row = c >> 3, kc = (c & 7) << 3;
            *(uint4*)(&As[row][kc]) =
                *(const uint4*)(AObf + (((size_t)(b * 8 + h) * 1024 + tt0 + row) << 6) + kc);
        }
        stage_f32(Wo, n0, k0, Bs, tid);
        __syncthreads();
        for (int kk = 0; kk < 2; ++kk) {
            bf16x8 af = *(const bf16x8*)(&As[arow][kk * 32 + quad * 8]);
            for (int nt = 0; nt < 4; ++nt) {
                bf16x8 bfv = *(const bf16x8*)(&Bs[nt * 16 + l16][kk * 32 + quad * 8]);
                acc[nt] = MFMA16(af, bfv, acc[nt]);
            }
        }
        __syncthreads();
    }
    for (int nt = 0; nt < 4; ++nt) {
        int col = n0 + nt * 16 + l16;
        float bv_ = bo[col];
        for (int reg = 0; reg < 4; ++reg) {
            int row = m0 + wave * 16 + quad * 4 + reg;
            out[(size_t)row * 512 + col] = acc[nt][reg] + bv_;
        }
    }
}

extern "C" void kernel_launch(void* const* d_in, const int* in_sizes, int n_in,
                              void* d_out, int out_size, void* d_ws, size_t ws_size,
                              hipStream_t stream) {
    // size-binder (measured: dict order, idx_x==0; keep both paths)
    const void* x = nullptr; const void* Ws[4] = {}; const void* bs[4] = {};
    const void* relT = nullptr;
    int wi = 0, bi = 0, idx_x = -1;
    for (int i = 0; i < n_in; ++i) {
        long s = in_sizes[i];
        if ((s == 2097152 || s == 8388608) && !x) { x = d_in[i]; idx_x = i; }
        else if ((s == 262144 || s == 1048576) && wi < 4) Ws[wi++] = d_in[i];
        else if ((s == 512 || s == 2048) && bi < 4) bs[bi++] = d_in[i];
        else if ((s == 32832 || s == 131328) && !relT) relT = d_in[i];
    }
    const float *Wq, *Wk, *Wv, *Wo, *bq, *bk, *bv, *bo;
    if (x && wi == 4 && bi == 4 && relT) {
        bool sorted_order = (idx_x != 0);
        if (sorted_order) {
            Wq = (const float*)Ws[2]; Wk = (const float*)Ws[0];
            Wv = (const float*)Ws[3]; Wo = (const float*)Ws[1];
            bq = (const float*)bs[2]; bk = (const float*)bs[0];
            bv = (const float*)bs[3]; bo = (const float*)bs[1];
        } else {
            Wq = (const float*)Ws[0]; Wk = (const float*)Ws[1];
            Wv = (const float*)Ws[2]; Wo = (const float*)Ws[3];
            bq = (const float*)bs[0]; bk = (const float*)bs[1];
            bv = (const float*)bs[2]; bo = (const float*)bs[3];
        }
    } else {
        x = d_in[0];
        Wq = (const float*)d_in[2]; bq = (const float*)d_in[3];
        Wk = (const float*)d_in[4]; bk = (const float*)d_in[5];
        Wv = (const float*)d_in[6]; bv = (const float*)d_in[7];
        Wo = (const float*)d_in[8]; bo = (const float*)d_in[9];
        relT = d_in[10];
    }
    const float* xf  = (const float*)x;
    const float* rel = (const float*)relT;
    float* out = (float*)d_out;              // FP32 OUTPUT

    // ws: 8KB + 8KB + 66KB + 3x4MB = 12.1 MB (known-safe footprint)
    char* ws = (char*)d_ws;
    float* xsum = (float*)(ws);
    float* Qsum = (float*)(ws + 8192);
    float* Rbuf = (float*)(ws + 16384);
    unsigned short* Qb = (unsigned short*)(ws + 131072);
    unsigned short* Kb = (unsigned short*)(ws + 131072 + (4 << 20));
    unsigned short* Vb = (unsigned short*)(ws + 131072 + (8 << 20));

    xsum_kernel<<<dim3(4), dim3(512), 0, stream>>>(xf, xsum);
    qsum_kernel<<<dim3(8), dim3(256), 0, stream>>>(xsum, Wq, bq, Qsum);
    rbias_kernel<<<dim3(65), dim3(256), 0, stream>>>(Qsum, rel, Rbuf);
    qkv_proj<<<dim3(8, 64, 3), dim3(256), 0, stream>>>(xf, Wq, bq, Wk, bk, Wv, bv, Qb, Kb, Vb);
    attn_kernel<<<dim3(16, 32), dim3(256), 0, stream>>>(Qb, Kb, Vb, Rbuf);
    out_proj<<<dim3(8, 64), dim3(256), 0, stream>>>(Qb, Wo, bo, out);
}

// Round 11
// 193.568 us; speedup vs baseline: 5.0618x; 1.2749x over previous
//
#include <hip/hip_runtime.h>
#include <stdint.h>

typedef __bf16  bf16x8 __attribute__((ext_vector_type(8)));
typedef float   f32x4  __attribute__((ext_vector_type(4)));

#define MFMA16(a, b, c) __builtin_amdgcn_mfma_f32_16x16x32_bf16((a), (b), (c), 0, 0, 0)

__device__ __forceinline__ float bf2f(unsigned short u) {
    union { unsigned u; float f; } v; v.u = ((unsigned)u) << 16; return v.f;
}
__device__ __forceinline__ unsigned short f2bf(float f) {
    union { float f; unsigned u; } v; v.f = f;
    unsigned r = v.u + 0x7fffu + ((v.u >> 16) & 1u);
    return (unsigned short)(r >> 16);
}

// B=4, T=1024, D=512, H=8, DH=64, MAX_REL=256.
// Inputs fp32 dict-order; OUTPUT FP32. MFMA pipeline (R10-verified, 247 us).
// R11: parallelize the latency-bound prologue (xsum 4->128 blocks, qsum/rbias wave-per-output).

// ---------- 1a. xsum partials: 4 x 32 blocks, 32 rows each ----------
__global__ __launch_bounds__(256) void xsum_part(const float* __restrict__ x,
                                                 float* __restrict__ part) {
    int b = blockIdx.x, chunk = blockIdx.y, k = threadIdx.x;   // (4, 32) x 256
    const float* p = x + (size_t)b * 1024 * 512 + (size_t)chunk * 32 * 512;
    float s0 = 0.f, s1 = 0.f;
    for (int t = 0; t < 32; ++t) {
        s0 += p[t * 512 + k];
        s1 += p[t * 512 + k + 256];
    }
    part[(size_t)(b * 32 + chunk) * 512 + k]       = s0;
    part[(size_t)(b * 32 + chunk) * 512 + k + 256] = s1;
}

// ---------- 1b. xsum reduce: 2048 outputs ----------
__global__ __launch_bounds__(256) void xsum_reduce(const float* __restrict__ part,
                                                   float* __restrict__ xsum) {
    int idx = blockIdx.x * 256 + threadIdx.x;      // 8 x 256
    int b = idx >> 9, k = idx & 511;
    float s = 0.f;
    for (int c = 0; c < 32; ++c) s += part[(size_t)(b * 32 + c) * 512 + k];
    xsum[idx] = s;
}

// ---------- 2. Qsum[b][n] = xsum[b]·Wq[n,:] + 1024*bq[n]  (wave per output) ----------
__global__ __launch_bounds__(256) void qsum_kernel(const float* __restrict__ xsum,
                                                   const float* __restrict__ Wq,
                                                   const float* __restrict__ bq,
                                                   float* __restrict__ Qsum) {
    int idx = blockIdx.x * 4 + (threadIdx.x >> 6);  // 512 blocks x 4 waves = 2048
    int lane = threadIdx.x & 63;
    int b = idx >> 9, n = idx & 511;
    const float* xs = xsum + b * 512;
    const float* w = Wq + (size_t)n * 512;
    float s = 0.f;
    for (int j = lane; j < 512; j += 64) s += xs[j] * w[j];
    for (int off = 32; off; off >>= 1) s += __shfl_xor(s, off, 64);
    if (lane == 0) Qsum[idx] = s + 1024.0f * bq[n];
}

// ---------- 3. R[bh*513+delta] = 0.125 * Qsum[b,h*64:+64]·rel_table[delta] (wave per out) ----------
__global__ __launch_bounds__(256) void rbias_kernel(const float* __restrict__ Qsum,
                                                    const float* __restrict__ relT,
                                                    float* __restrict__ R) {
    int idx = blockIdx.x * 4 + (threadIdx.x >> 6);  // 4104 blocks x 4 waves >= 16416
    if (idx >= 4 * 8 * 513) return;
    int lane = threadIdx.x & 63;
    int delta = idx % 513, bh = idx / 513;
    int b = bh >> 3, h = bh & 7;
    float s = Qsum[b * 512 + h * 64 + lane] * relT[(size_t)delta * 64 + lane];
    for (int off = 32; off; off >>= 1) s += __shfl_xor(s, off, 64);
    if (lane == 0) R[idx] = 0.125f * s;
}

// ---------- fp32 64x64 tile (ld=512) -> bf16 LDS [64][72] ----------
__device__ __forceinline__ void stage_f32(const float* __restrict__ src, int row0, int k0,
                                          unsigned short (*dst)[72], int tid) {
    for (int c = tid; c < 1024; c += 256) {
        int row = c >> 4, kc = (c & 15) << 2;
        f32x4 v = *(const f32x4*)(src + (size_t)(row0 + row) * 512 + k0 + kc);
        ushort4 r;
        r.x = f2bf(v[0]); r.y = f2bf(v[1]); r.z = f2bf(v[2]); r.w = f2bf(v[3]);
        *(ushort4*)(&dst[row][kc]) = r;
    }
}

// ---------- 4. QKV projection (MFMA): y = x @ W^T + b -> (B,H,T,DH) bf16 ----------
__global__ __launch_bounds__(256) void qkv_proj(
    const float* __restrict__ x,
    const float* __restrict__ Wq, const float* __restrict__ bq,
    const float* __restrict__ Wk, const float* __restrict__ bk,
    const float* __restrict__ Wv, const float* __restrict__ bv,
    unsigned short* __restrict__ Qb, unsigned short* __restrict__ Kb, unsigned short* __restrict__ Vb) {
    const int which = blockIdx.z;
    const float* W; const float* bias; unsigned short* Out;
    if (which == 0)      { W = Wq; bias = bq; Out = Qb; }
    else if (which == 1) { W = Wk; bias = bk; Out = Kb; }
    else                 { W = Wv; bias = bv; Out = Vb; }
    const int m0 = blockIdx.y * 64;
    const int n0 = blockIdx.x * 64;

    __shared__ __align__(16) unsigned short As[64][72];
    __shared__ __align__(16) unsigned short Bs[64][72];

    int tid = threadIdx.x;
    int wave = tid >> 6, lane = tid & 63, quad = lane >> 4, l16 = lane & 15;
    int arow = wave * 16 + l16;

    f32x4 acc[4] = {};

    for (int k0 = 0; k0 < 512; k0 += 64) {
        stage_f32(x, m0, k0, As, tid);
        stage_f32(W, n0, k0, Bs, tid);
        __syncthreads();
        for (int kk = 0; kk < 2; ++kk) {
            bf16x8 af = *(const bf16x8*)(&As[arow][kk * 32 + quad * 8]);
            for (int nt = 0; nt < 4; ++nt) {
                bf16x8 bfv = *(const bf16x8*)(&Bs[nt * 16 + l16][kk * 32 + quad * 8]);
                acc[nt] = MFMA16(af, bfv, acc[nt]);
            }
        }
        __syncthreads();
    }
    for (int nt = 0; nt < 4; ++nt) {
        int col = n0 + nt * 16 + l16;
        int h = col >> 6, d = col & 63;
        float bv_ = bias[col];
        for (int reg = 0; reg < 4; ++reg) {
            int row = m0 + wave * 16 + quad * 4 + reg;     // = b*1024 + t
            int b = row >> 10, t = row & 1023;
            Out[(((size_t)(b * 8 + h) * 1024 + t) << 6) + d] = f2bf(acc[nt][reg] + bv_);
        }
    }
}

// ---------- 5. MFMA flash attention per (b,h, 64-row q-tile); AO overwrites Qb slice ----------
__global__ __launch_bounds__(256) void attn_kernel(
    unsigned short* __restrict__ Qb,                     // in: Q, out: AO (block-private slice)
    const unsigned short* __restrict__ Kb, const unsigned short* __restrict__ Vb,
    const float* __restrict__ R) {
    const int bh = blockIdx.y;
    const int t0 = blockIdx.x * 64;
    __shared__ __align__(16) unsigned short Ks[64][72];
    __shared__ __align__(16) unsigned short Vt[64][72];
    __shared__ __align__(16) unsigned short Ps[64][72];
    __shared__ float Rs[513];

    int tid = threadIdx.x, wave = tid >> 6, lane = tid & 63, quad = lane >> 4, l16 = lane & 15;

    for (int i = tid; i < 513; i += 256) Rs[i] = R[bh * 513 + i];

    unsigned short* Qp = Qb + ((size_t)bh * 1024 + t0) * 64;
    int arow = wave * 16 + l16;
    bf16x8 qf0 = *(const bf16x8*)(Qp + arow * 64 + quad * 8);
    bf16x8 qf1 = *(const bf16x8*)(Qp + arow * 64 + 32 + quad * 8);

    const unsigned short* Kp = Kb + (size_t)bh * 1024 * 64;
    const unsigned short* Vp = Vb + (size_t)bh * 1024 * 64;

    f32x4 acco[4] = {};
    float m_run[4], l_run[4];
    for (int r = 0; r < 4; ++r) { m_run[r] = -1e30f; l_run[r] = 0.f; }

    for (int s0 = 0; s0 < 1024; s0 += 64) {
        __syncthreads();
        for (int c = tid; c < 512; c += 256) {
            int row = c >> 3, kc = (c & 7) << 3;
            *(uint4*)(&Ks[row][kc]) = *(const uint4*)(Kp + (size_t)(s0 + row) * 64 + kc);
            uint4 vv = *(const uint4*)(Vp + (size_t)(s0 + row) * 64 + kc);
            const unsigned short* ve = (const unsigned short*)&vv;
            for (int j = 0; j < 8; ++j) Vt[kc + j][row] = ve[j];
        }
        __syncthreads();

        f32x4 accs[4] = {};
        for (int nt = 0; nt < 4; ++nt) {
            bf16x8 kf0 = *(const bf16x8*)(&Ks[nt * 16 + l16][quad * 8]);
            accs[nt] = MFMA16(qf0, kf0, accs[nt]);
            bf16x8 kf1 = *(const bf16x8*)(&Ks[nt * 16 + l16][32 + quad * 8]);
            accs[nt] = MFMA16(qf1, kf1, accs[nt]);
        }

        float sv[4][4], mnew[4], alpha[4];
        for (int reg = 0; reg < 4; ++reg) {
            int tt = t0 + wave * 16 + quad * 4 + reg;
            float mx = -1e30f;
            for (int nt = 0; nt < 4; ++nt) {
                int ss = s0 + nt * 16 + l16;
                int dlt = ss - tt;
                dlt = dlt > 256 ? 256 : (dlt < -256 ? -256 : dlt);
                float v = accs[nt][reg] * 0.125f + Rs[dlt + 256];
                sv[nt][reg] = v;
                mx = fmaxf(mx, v);
            }
            for (int off = 1; off < 16; off <<= 1) mx = fmaxf(mx, __shfl_xor(mx, off, 64));
            mnew[reg] = fmaxf(m_run[reg], mx);
        }
        for (int reg = 0; reg < 4; ++reg) {
            float rs = 0.f;
            for (int nt = 0; nt < 4; ++nt) {
                float p = __expf(sv[nt][reg] - mnew[reg]);
                rs += p;
                Ps[wave * 16 + quad * 4 + reg][nt * 16 + l16] = f2bf(p);
            }
            for (int off = 1; off < 16; off <<= 1) rs += __shfl_xor(rs, off, 64);
            alpha[reg] = __expf(m_run[reg] - mnew[reg]);
            l_run[reg] = l_run[reg] * alpha[reg] + rs;
            m_run[reg] = mnew[reg];
        }
        for (int nt = 0; nt < 4; ++nt)
            for (int reg = 0; reg < 4; ++reg) acco[nt][reg] *= alpha[reg];

        __syncthreads();

        for (int kk = 0; kk < 2; ++kk) {
            bf16x8 pf = *(const bf16x8*)(&Ps[wave * 16 + l16][kk * 32 + quad * 8]);
            for (int nt = 0; nt < 4; ++nt) {
                bf16x8 vf = *(const bf16x8*)(&Vt[nt * 16 + l16][kk * 32 + quad * 8]);
                acco[nt] = MFMA16(pf, vf, acco[nt]);
            }
        }
    }

    for (int nt = 0; nt < 4; ++nt) {
        for (int reg = 0; reg < 4; ++reg) {
            int tt = t0 + wave * 16 + quad * 4 + reg;
            int d = nt * 16 + l16;
            Qb[((size_t)bh * 1024 + tt) * 64 + d] = f2bf(acco[nt][reg] / l_run[reg]);
        }
    }
}

// ---------- 6. output projection (MFMA): out = AO_headconcat @ Wo^T + bo, fp32 ----------
__global__ __launch_bounds__(256) void out_proj(
    const unsigned short* __restrict__ AObf, const float* __restrict__ Wo,
    const float* __restrict__ bo, float* __restrict__ out) {
    const int m0 = blockIdx.y * 64;
    const int n0 = blockIdx.x * 64;
    const int b = m0 >> 10, tt0 = m0 & 1023;
    __shared__ __align__(16) unsigned short As[64][72];
    __shared__ __align__(16) unsigned short Bs[64][72];
    int tid = threadIdx.x, wave = tid >> 6, lane = tid & 63, quad = lane >> 4, l16 = lane & 15;
    int arow = wave * 16 + l16;
    f32x4 acc[4] = {};
    for (int k0 = 0; k0 < 512; k0 += 64) {
        const int h = k0 >> 6;
        for (int c = tid; c < 512; c += 256) {
            int row = c >> 3, kc = (c & 7) << 3;
            *(uint4*)(&As[row][kc]) =
                *(const uint4*)(AObf + (((size_t)(b * 8 + h) * 1024 + tt0 + row) << 6) + kc);
        }
        stage_f32(Wo, n0, k0, Bs, tid);
        __syncthreads();
        for (int kk = 0; kk < 2; ++kk) {
            bf16x8 af = *(const bf16x8*)(&As[arow][kk * 32 + quad * 8]);
            for (int nt = 0; nt < 4; ++nt) {
                bf16x8 bfv = *(const bf16x8*)(&Bs[nt * 16 + l16][kk * 32 + quad * 8]);
                acc[nt] = MFMA16(af, bfv, acc[nt]);
            }
        }
        __syncthreads();
    }
    for (int nt = 0; nt < 4; ++nt) {
        int col = n0 + nt * 16 + l16;
        float bv_ = bo[col];
        for (int reg = 0; reg < 4; ++reg) {
            int row = m0 + wave * 16 + quad * 4 + reg;
            out[(size_t)row * 512 + col] = acc[nt][reg] + bv_;
        }
    }
}

extern "C" void kernel_launch(void* const* d_in, const int* in_sizes, int n_in,
                              void* d_out, int out_size, void* d_ws, size_t ws_size,
                              hipStream_t stream) {
    const void* x = nullptr; const void* Ws[4] = {}; const void* bs[4] = {};
    const void* relT = nullptr;
    int wi = 0, bi = 0, idx_x = -1;
    for (int i = 0; i < n_in; ++i) {
        long s = in_sizes[i];
        if ((s == 2097152 || s == 8388608) && !x) { x = d_in[i]; idx_x = i; }
        else if ((s == 262144 || s == 1048576) && wi < 4) Ws[wi++] = d_in[i];
        else if ((s == 512 || s == 2048) && bi < 4) bs[bi++] = d_in[i];
        else if ((s == 32832 || s == 131328) && !relT) relT = d_in[i];
    }
    const float *Wq, *Wk, *Wv, *Wo, *bq, *bk, *bv, *bo;
    if (x && wi == 4 && bi == 4 && relT) {
        bool sorted_order = (idx_x != 0);    // measured: dict order (idx_x==0)
        if (sorted_order) {
            Wq = (const float*)Ws[2]; Wk = (const float*)Ws[0];
            Wv = (const float*)Ws[3]; Wo = (const float*)Ws[1];
            bq = (const float*)bs[2]; bk = (const float*)bs[0];
            bv = (const float*)bs[3]; bo = (const float*)bs[1];
        } else {
            Wq = (const float*)Ws[0]; Wk = (const float*)Ws[1];
            Wv = (const float*)Ws[2]; Wo = (const float*)Ws[3];
            bq = (const float*)bs[0]; bk = (const float*)bs[1];
            bv = (const float*)bs[2]; bo = (const float*)bs[3];
        }
    } else {
        x = d_in[0];
        Wq = (const float*)d_in[2]; bq = (const float*)d_in[3];
        Wk = (const float*)d_in[4]; bk = (const float*)d_in[5];
        Wv = (const float*)d_in[6]; bv = (const float*)d_in[7];
        Wo = (const float*)d_in[8]; bo = (const float*)d_in[9];
        relT = d_in[10];
    }
    const float* xf  = (const float*)x;
    const float* rel = (const float*)relT;
    float* out = (float*)d_out;

    // ws: xsum 8K | Qsum 8K | Rbuf 66K | Qb/Kb/Vb 3x4M | part 256K  (total ~12.4 MB)
    char* ws = (char*)d_ws;
    float* xsum = (float*)(ws);
    float* Qsum = (float*)(ws + 8192);
    float* Rbuf = (float*)(ws + 16384);
    unsigned short* Qb = (unsigned short*)(ws + 131072);
    unsigned short* Kb = (unsigned short*)(ws + 131072 + (4 << 20));
    unsigned short* Vb = (unsigned short*)(ws + 131072 + (8 << 20));
    float* part = (float*)(ws + 131072 + (12 << 20));   // 4*32*512 fp32 = 256 KB

    xsum_part<<<dim3(4, 32), dim3(256), 0, stream>>>(xf, part);
    xsum_reduce<<<dim3(8), dim3(256), 0, stream>>>(part, xsum);
    qsum_kernel<<<dim3(512), dim3(256), 0, stream>>>(xsum, Wq, bq, Qsum);
    rbias_kernel<<<dim3(4104), dim3(256), 0, stream>>>(Qsum, rel, Rbuf);
    qkv_proj<<<dim3(8, 64, 3), dim3(256), 0, stream>>>(xf, Wq, bq, Wk, bk, Wv, bv, Qb, Kb, Vb);
    attn_kernel<<<dim3(16, 32), dim3(256), 0, stream>>>(Qb, Kb, Vb, Rbuf);
    out_proj<<<dim3(8, 64), dim3(256), 0, stream>>>(Qb, Wo, bo, out);
}